// Round 1
// baseline (4344.357 us; speedup 1.0000x reference)
//
#include <hip/hip_runtime.h>
#include <math.h>

// Problem constants
constexpr int Bsz = 8, Tn = 16, Hh = 32, Ww = 32, CINc = 6, Fc = 64, NCc = 10;
constexpr int PIX = Bsz * Hh * Ww;     // 8192 pixels per timestep (all batches)
constexpr int NCH = 4 * Fc;            // 256 gate channels
constexpr float BN_EPS = 1e-3f;

__device__ __forceinline__ float hsig(float x) {
    return fminf(fmaxf(0.2f * x + 0.5f, 0.0f), 1.0f);
}

// ---------------- init: zero states + output ----------------
__global__ void init_zero(float* h0, float* c0, float* h1, float* c1, float* out) {
    int i = blockIdx.x * 256 + threadIdx.x;
    if (i < PIX * Fc) { h0[i] = 0.f; c0[i] = 0.f; h1[i] = 0.f; c1[i] = 0.f; }
    if (i < Bsz * NCc) out[i] = 0.f;
}

// ---------------- conv GEMM ----------------
// z[8192][256] = conv3x3(X, Wx) + conv3x3(Hb, Wh) + bias
// X:  base pointer already offset to timestep t; pixel (b,y,x,c) at
//     b*xBStride + (y*32+x)*xCh + c
// Hb: [8192][64], pixel = b*1024 + y*32 + x
// W layout HWIO: ((tap)*Ch + c)*256 + n, tap = dy*3+dx, dy,dx in 0..2
// Tile: 64 pixels (8x8 spatial) x 64 out-channels; 256 threads, 4x4 reg tile.
__global__ __launch_bounds__(256) void conv_gemm(
    const float* __restrict__ X, int xCh, int xBStride,
    const float* __restrict__ Hb,
    const float* __restrict__ Wx, const float* __restrict__ Wh,
    const float* __restrict__ bias,
    float* __restrict__ Z)
{
    __shared__ float As[16][68];   // [k][pixel], padded row=68 (272B, 16B-aligned)
    __shared__ float Bs[16][64];   // [k][n]

    const int tid = threadIdx.x;
    const int ty = tid >> 4, tx = tid & 15;
    const int bm = blockIdx.x >> 2, bn = blockIdx.x & 3;
    const int img = bm >> 4, ti = bm & 15;
    const int y0 = (ti >> 2) * 8, x0 = (ti & 3) * 8;

    float acc[4][4];
#pragma unroll
    for (int i = 0; i < 4; ++i)
#pragma unroll
        for (int j = 0; j < 4; ++j) acc[i][j] = 0.f;

    for (int tap = 0; tap < 9; ++tap) {
        const int dy = tap / 3 - 1, dx = tap % 3 - 1;
        for (int src = 0; src < 2; ++src) {
            const float* __restrict__ P = src ? Hb : X;
            const int Ch   = src ? Fc : xCh;
            const int bStr = src ? (1024 * Fc) : xBStride;
            const float* __restrict__ W = src ? Wh : Wx;
            const int nChunk = (Ch + 15) >> 4;
            for (int cc = 0; cc < nChunk; ++cc) {
                const int c0 = cc << 4;
                // stage A (transposed): As[k][p]
#pragma unroll
                for (int e = 0; e < 4; ++e) {
                    int flat = tid + e * 256;
                    int k = flat & 15, p = flat >> 4;
                    int gy = y0 + (p >> 3) + dy, gx = x0 + (p & 7) + dx;
                    int c = c0 + k;
                    float v = 0.f;
                    if ((unsigned)gy < 32u && (unsigned)gx < 32u && c < Ch)
                        v = P[img * bStr + (gy * 32 + gx) * Ch + c];
                    As[k][p] = v;
                }
                // stage B: Bs[k][n]
#pragma unroll
                for (int e = 0; e < 4; ++e) {
                    int flat = tid + e * 256;
                    int n = flat & 63, k = flat >> 6;
                    int c = c0 + k;
                    float v = 0.f;
                    if (c < Ch)
                        v = W[(tap * Ch + c) * 256 + bn * 64 + n];
                    Bs[k][n] = v;
                }
                __syncthreads();
#pragma unroll
                for (int k = 0; k < 16; ++k) {
                    float4 a4 = *(const float4*)&As[k][ty * 4];
                    float4 b4 = *(const float4*)&Bs[k][tx * 4];
                    float av[4] = {a4.x, a4.y, a4.z, a4.w};
                    float bv[4] = {b4.x, b4.y, b4.z, b4.w};
#pragma unroll
                    for (int i = 0; i < 4; ++i)
#pragma unroll
                        for (int j = 0; j < 4; ++j)
                            acc[i][j] += av[i] * bv[j];
                }
                __syncthreads();
            }
        }
    }
    // epilogue: + bias, write Z
    const float4 bb = *(const float4*)&bias[bn * 64 + tx * 4];
    const float bv[4] = {bb.x, bb.y, bb.z, bb.w};
#pragma unroll
    for (int i = 0; i < 4; ++i) {
        int m = ty * 4 + i;
        int pix = img * 1024 + (y0 + (m >> 3)) * 32 + (x0 + (m & 7));
        float4 o;
        o.x = acc[i][0] + bv[0];
        o.y = acc[i][1] + bv[1];
        o.z = acc[i][2] + bv[2];
        o.w = acc[i][3] + bv[3];
        *(float4*)&Z[pix * 256 + bn * 64 + tx * 4] = o;
    }
}

// ---------------- gates: z -> (c, h), optionally BN(h) -> X1out ----------------
__global__ __launch_bounds__(256) void gates_kernel(
    const float* __restrict__ Z, float* __restrict__ C,
    float* __restrict__ Hout, float* __restrict__ X1out,
    const float* __restrict__ gamma, const float* __restrict__ beta,
    const float* __restrict__ mean, const float* __restrict__ var)
{
    int idx = blockIdx.x * 256 + threadIdx.x;
    if (idx >= PIX * Fc) return;
    int pix = idx >> 6, ch = idx & 63;
    const float* zp = Z + pix * 256 + ch;
    float zi = zp[0], zf = zp[64], zg = zp[128], zo = zp[192];
    float ig = hsig(zi), fg = hsig(zf), og = hsig(zo), gg = tanhf(zg);
    float c = fg * C[idx] + ig * gg;
    C[idx] = c;
    float h = og * tanhf(c);
    Hout[idx] = h;
    if (X1out) {
        float inv = gamma[ch] * rsqrtf(var[ch] + BN_EPS);
        X1out[idx] = (h - mean[ch]) * inv + beta[ch];
    }
}

// ---------------- pool: BN1(h1) @ denseW -> softmax -> accumulate mean ----------------
__global__ __launch_bounds__(256) void pool_kernel(
    const float* __restrict__ H1, const float* __restrict__ dW,
    const float* __restrict__ dB,
    const float* __restrict__ gamma, const float* __restrict__ beta,
    const float* __restrict__ mean, const float* __restrict__ var,
    float* __restrict__ out)
{
    __shared__ float accs[NCc];
    int pix = blockIdx.x * 256 + threadIdx.x;   // 32 blocks x 256 = 8192
    int b = pix >> 10;                          // all pixels in block share b
    if (threadIdx.x < NCc) accs[threadIdx.x] = 0.f;
    __syncthreads();

    float logit[NCc];
#pragma unroll
    for (int c = 0; c < NCc; ++c) logit[c] = dB[c];
    for (int f = 0; f < Fc; ++f) {
        float inv = gamma[f] * rsqrtf(var[f] + BN_EPS);
        float v = (H1[pix * Fc + f] - mean[f]) * inv + beta[f];
#pragma unroll
        for (int c = 0; c < NCc; ++c) logit[c] += v * dW[f * NCc + c];
    }
    float mx = logit[0];
#pragma unroll
    for (int c = 1; c < NCc; ++c) mx = fmaxf(mx, logit[c]);
    float p[NCc]; float s = 0.f;
#pragma unroll
    for (int c = 0; c < NCc; ++c) { p[c] = expf(logit[c] - mx); s += p[c]; }
    float invs = 1.f / s;
#pragma unroll
    for (int c = 0; c < NCc; ++c) atomicAdd(&accs[c], p[c] * invs);
    __syncthreads();
    if (threadIdx.x < NCc)
        atomicAdd(&out[b * NCc + threadIdx.x], accs[threadIdx.x] * (1.0f / 16384.0f));
}

extern "C" void kernel_launch(void* const* d_in, const int* in_sizes, int n_in,
                              void* d_out, int out_size, void* d_ws, size_t ws_size,
                              hipStream_t stream) {
    const float* in    = (const float*)d_in[0];
    const float* l0Wx  = (const float*)d_in[1];
    const float* l0Wh  = (const float*)d_in[2];
    const float* l0b   = (const float*)d_in[3];
    const float* l0g   = (const float*)d_in[4];
    const float* l0be  = (const float*)d_in[5];
    const float* l0m   = (const float*)d_in[6];
    const float* l0v   = (const float*)d_in[7];
    const float* l1Wx  = (const float*)d_in[8];
    const float* l1Wh  = (const float*)d_in[9];
    const float* l1b   = (const float*)d_in[10];
    const float* l1g   = (const float*)d_in[11];
    const float* l1be  = (const float*)d_in[12];
    const float* l1m   = (const float*)d_in[13];
    const float* l1v   = (const float*)d_in[14];
    const float* dW    = (const float*)d_in[15];
    const float* dB    = (const float*)d_in[16];
    float* out = (float*)d_out;

    float* ws    = (float*)d_ws;
    float* zbuf  = ws;                       // 8192*256   = 2,097,152 f
    float* h0    = zbuf + 2097152;           // 524,288 f
    float* c0    = h0 + 524288;
    float* h1    = c0 + 524288;
    float* c1    = h1 + 524288;
    float* x1seq = c1 + 524288;              // 16 * 524,288 f

    init_zero<<<2048, 256, 0, stream>>>(h0, c0, h1, c1, out);

    // Layer 0: input = raw inputs [8,16,32,32,6]
    for (int t = 0; t < Tn; ++t) {
        const float* xt = in + t * (Hh * Ww * CINc);   // batch stride below
        conv_gemm<<<512, 256, 0, stream>>>(xt, CINc, Tn * Hh * Ww * CINc,
                                           h0, l0Wx, l0Wh, l0b, zbuf);
        gates_kernel<<<2048, 256, 0, stream>>>(zbuf, c0, h0, x1seq + t * (PIX * Fc),
                                               l0g, l0be, l0m, l0v);
    }
    // Layer 1: input = BN(layer0 h), stored as x1seq [t][8192][64]
    for (int t = 0; t < Tn; ++t) {
        conv_gemm<<<512, 256, 0, stream>>>(x1seq + t * (PIX * Fc), Fc, Hh * Ww * Fc,
                                           h1, l1Wx, l1Wh, l1b, zbuf);
        gates_kernel<<<2048, 256, 0, stream>>>(zbuf, c1, h1, nullptr,
                                               nullptr, nullptr, nullptr, nullptr);
        pool_kernel<<<32, 256, 0, stream>>>(h1, dW, dB, l1g, l1be, l1m, l1v, out);
    }
}

// Round 2
// 1261.813 us; speedup vs baseline: 3.4429x; 3.4429x over previous
//
#include <hip/hip_runtime.h>
#include <math.h>

typedef __attribute__((ext_vector_type(8))) short short8v;   // 8 bf16 = 4 VGPRs
typedef __attribute__((ext_vector_type(4))) float float4v;   // MFMA acc

constexpr int Bsz = 8, Tn = 16, CINc = 6, Fc = 64, NCc = 10;
constexpr int PIX = 8192;                 // 8*32*32 pixels per timestep
constexpr float BN_EPS = 1e-3f;

// weight-fragment region offsets (in ushort elements)
constexpr int FR_L0X = 0;                 // 2 chunks  (K=54 padded to 64)
constexpr int FR_L0H = 16384;             // 18 chunks (K=576)
constexpr int FR_L1X = 163840;            // 18 chunks
constexpr int FR_L1H = 311296;            // 18 chunks
constexpr int FR_TOTAL = 458752;

__device__ __forceinline__ ushort f2bf(float f) {
    union { float f; unsigned u; } v; v.f = f;
    unsigned r = v.u + 0x7FFFu + ((v.u >> 16) & 1u);   // RNE
    return (ushort)(r >> 16);
}
__device__ __forceinline__ float bf2f(ushort u) {
    union { unsigned u; float f; } v; v.u = ((unsigned)u) << 16; return v.f;
}
__device__ __forceinline__ float hsig(float x) {
    return fminf(fmaxf(0.2f * x + 0.5f, 0.0f), 1.0f);
}

// ---------------- prep: x -> bf16 [t][pix][6] ----------------
__global__ __launch_bounds__(256) void prep_x(const float* __restrict__ in,
                                              ushort* __restrict__ xb) {
    int o = blockIdx.x * 256 + threadIdx.x;        // 16*8192*6 = 786432
    if (o >= Tn * PIX * CINc) return;
    int t = o / (PIX * CINc);
    int rem = o - t * (PIX * CINc);
    int pix = rem / CINc, c = rem - pix * CINc;
    int b = pix >> 10, p = pix & 1023;
    xb[o] = f2bf(in[((b * Tn + t) * 1024 + p) * CINc + c]);
}

// ---------------- prep: weights -> B-fragment layout ----------------
// frag element (kc, nt, lane, e): k = kc*32 + (lane>>4)*4 + (e&3) + 16*(e>>2),
// n = nt*16 + (lane&15); value = k<K ? W[k*256+n] : 0   (W is HWIO flat: k=tap*Ch+c)
__global__ __launch_bounds__(256) void prep_w(const float* __restrict__ W0x,
                                              const float* __restrict__ W0h,
                                              const float* __restrict__ W1x,
                                              const float* __restrict__ W1h,
                                              ushort* __restrict__ F) {
    int o = blockIdx.x * 256 + threadIdx.x;
    if (o >= FR_TOTAL) return;
    const float* W; int K; int base;
    if (o < FR_L0H)      { W = W0x; K = 54;  base = FR_L0X; }
    else if (o < FR_L1X) { W = W0h; K = 576; base = FR_L0H; }
    else if (o < FR_L1H) { W = W1x; K = 576; base = FR_L1X; }
    else                 { W = W1h; K = 576; base = FR_L1H; }
    int r = o - base;
    int e = r & 7, lane = (r >> 3) & 63, fi = r >> 9;     // fi = kc*16 + nt
    int kc = fi >> 4, nt = fi & 15;
    int k = kc * 32 + ((lane >> 4) * 4) + (e & 3) + 16 * (e >> 2);
    int n = nt * 16 + (lane & 15);
    F[o] = (k < K) ? f2bf(W[k * 256 + n]) : (ushort)0;
}

// ---------------- init ----------------
__global__ __launch_bounds__(256) void init_zero(float* c0, float* c1,
                                                 ushort* h0, ushort* h1, float* out) {
    int i = blockIdx.x * 256 + threadIdx.x;
    if (i < PIX * Fc) { c0[i] = 0.f; c1[i] = 0.f; h0[i] = 0; h1[i] = 0; }
    if (i < Bsz * NCc) out[i] = 0.f;
}

// ---------------- conv via MFMA ----------------
// Z[8192][256] = conv3x3(X,Wx) + conv3x3(H,Wh) + bias
// tile: 64 pixels x 64 out-channels, 4 waves (wave = 16 pix x 64 ch)
__global__ __launch_bounds__(256) void conv_mfma(
    const ushort* __restrict__ Ax, int xCh, int xChunks, const ushort* __restrict__ BfX,
    const ushort* __restrict__ Ah, const ushort* __restrict__ BfH,
    const float* __restrict__ bias, float* __restrict__ Z)
{
    __shared__ ushort As[64 * 40];   // 64 pixel-rows x 32 k (+8 pad) = 80B rows

    const int tid = threadIdx.x;
    const int bm = blockIdx.x >> 2, bn = blockIdx.x & 3;
    const int m0 = bm * 64;
    const int wid = tid >> 6, lane = tid & 63;

    // staging coords: thread stages pixel p_local, k-quarter kq (8 bf16)
    const int p_local = tid >> 2, kq = tid & 3;
    const int p_global = m0 + p_local;
    const int img = p_global >> 10, pp = p_global & 1023;
    const int py = pp >> 5, px = pp & 31;

    // A-fragment read address (bytes): row = wid*16 + (lane&15), col-half by lane>>4
    const int arow_byte = (wid * 16 + (lane & 15)) * 80 + (lane >> 4) * 8;

    float4v acc[4];
#pragma unroll
    for (int j = 0; j < 4; ++j)
#pragma unroll
        for (int r = 0; r < 4; ++r) acc[j][r] = 0.f;

    for (int src = 0; src < 2; ++src) {
        const ushort* __restrict__ P  = src ? Ah : Ax;
        const ushort* __restrict__ Bf = src ? BfH : BfX;
        const int Ch  = src ? Fc : xCh;
        const int nch = src ? 18 : xChunks;

        for (int kc = 0; kc < nch; ++kc) {
            // issue B-fragment loads early (global, L2-resident)
            uint4 bfr[4];
#pragma unroll
            for (int j = 0; j < 4; ++j)
                bfr[j] = *(const uint4*)(Bf + (((kc * 16 + bn * 4 + j) * 64 + lane) << 3));

            // gather A chunk into registers
            uint4 av = make_uint4(0u, 0u, 0u, 0u);
            if (Ch == 64) {
                const int tap = kc >> 1;                       // uniform per chunk
                const int c0 = ((kc & 1) << 5) + (kq << 3);
                const int dy = tap / 3 - 1, dx = tap % 3 - 1;
                const int gy = py + dy, gx = px + dx;
                if ((unsigned)gy < 32u && (unsigned)gx < 32u)
                    av = *(const uint4*)(P + (((img << 10) + gy * 32 + gx) << 6) + c0);
            } else {
                // Ch==6 (layer-0 X), K=54 padded to 64
                ushort tmp[8];
#pragma unroll
                for (int j = 0; j < 8; ++j) {
                    int kg = kc * 32 + kq * 8 + j;
                    ushort v = 0;
                    if (kg < 54) {
                        int tap = kg / 6, c = kg - tap * 6;
                        int dy = tap / 3 - 1, dx = tap % 3 - 1;
                        int gy = py + dy, gx = px + dx;
                        if ((unsigned)gy < 32u && (unsigned)gx < 32u)
                            v = P[((img << 10) + gy * 32 + gx) * 6 + c];
                    }
                    tmp[j] = v;
                }
                union { ushort s[8]; uint4 u; } pk;
#pragma unroll
                for (int j = 0; j < 8; ++j) pk.s[j] = tmp[j];
                av = pk.u;
            }

            __syncthreads();   // previous iteration's LDS reads done
            *(uint4*)((char*)As + p_local * 80 + kq * 16) = av;
            __syncthreads();   // A tile visible

            // A fragment: two b64 reads (k 0-15 half, k 16-31 half)
            union { struct { uint2 lo, hi; } u; short8v s; } afr;
            afr.u.lo = *(const uint2*)((const char*)As + arow_byte);
            afr.u.hi = *(const uint2*)((const char*)As + arow_byte + 32);

#pragma unroll
            for (int j = 0; j < 4; ++j) {
                union { uint4 u; short8v s; } b; b.u = bfr[j];
                acc[j] = __builtin_amdgcn_mfma_f32_16x16x32_bf16(afr.s, b.s, acc[j], 0, 0, 0);
            }
        }
    }

    // epilogue: + bias -> Z (fp32)
#pragma unroll
    for (int j = 0; j < 4; ++j) {
        const int n = bn * 64 + j * 16 + (lane & 15);
        const float bb = bias[n];
#pragma unroll
        for (int r = 0; r < 4; ++r) {
            const int pix = m0 + wid * 16 + (lane >> 4) * 4 + r;
            Z[pix * 256 + n] = acc[j][r] + bb;
        }
    }
}

// ---------------- gates ----------------
__global__ __launch_bounds__(256) void gates_kernel(
    const float* __restrict__ Z, float* __restrict__ C,
    ushort* __restrict__ Hout, ushort* __restrict__ X1out,
    const float* __restrict__ gamma, const float* __restrict__ beta,
    const float* __restrict__ mean, const float* __restrict__ var)
{
    int idx = blockIdx.x * 256 + threadIdx.x;
    if (idx >= PIX * Fc) return;
    int pix = idx >> 6, ch = idx & 63;
    const float* zp = Z + pix * 256 + ch;
    float zi = zp[0], zf = zp[64], zg = zp[128], zo = zp[192];
    float ig = hsig(zi), fg = hsig(zf), og = hsig(zo), gg = tanhf(zg);
    float c = fg * C[idx] + ig * gg;
    C[idx] = c;
    float h = og * tanhf(c);
    Hout[idx] = f2bf(h);
    if (X1out) {
        float inv = gamma[ch] * rsqrtf(var[ch] + BN_EPS);
        X1out[idx] = f2bf((h - mean[ch]) * inv + beta[ch]);
    }
}

// ---------------- pool: BN1(h1) @ denseW -> softmax -> mean ----------------
__global__ __launch_bounds__(256) void pool_kernel(
    const ushort* __restrict__ H1, const float* __restrict__ dW,
    const float* __restrict__ dB,
    const float* __restrict__ gamma, const float* __restrict__ beta,
    const float* __restrict__ mean, const float* __restrict__ var,
    float* __restrict__ out)
{
    __shared__ float accs[NCc];
    int pix = blockIdx.x * 256 + threadIdx.x;   // 32 blocks x 256 = 8192
    int b = pix >> 10;
    if (threadIdx.x < NCc) accs[threadIdx.x] = 0.f;
    __syncthreads();

    float logit[NCc];
#pragma unroll
    for (int c = 0; c < NCc; ++c) logit[c] = dB[c];
    for (int f = 0; f < Fc; ++f) {
        float inv = gamma[f] * rsqrtf(var[f] + BN_EPS);
        float v = (bf2f(H1[pix * Fc + f]) - mean[f]) * inv + beta[f];
#pragma unroll
        for (int c = 0; c < NCc; ++c) logit[c] += v * dW[f * NCc + c];
    }
    float mx = logit[0];
#pragma unroll
    for (int c = 1; c < NCc; ++c) mx = fmaxf(mx, logit[c]);
    float p[NCc]; float s = 0.f;
#pragma unroll
    for (int c = 0; c < NCc; ++c) { p[c] = expf(logit[c] - mx); s += p[c]; }
    float invs = 1.f / s;
#pragma unroll
    for (int c = 0; c < NCc; ++c) atomicAdd(&accs[c], p[c] * invs);
    __syncthreads();
    if (threadIdx.x < NCc)
        atomicAdd(&out[b * NCc + threadIdx.x], accs[threadIdx.x] * (1.0f / 16384.0f));
}

extern "C" void kernel_launch(void* const* d_in, const int* in_sizes, int n_in,
                              void* d_out, int out_size, void* d_ws, size_t ws_size,
                              hipStream_t stream) {
    const float* in    = (const float*)d_in[0];
    const float* l0Wx  = (const float*)d_in[1];
    const float* l0Wh  = (const float*)d_in[2];
    const float* l0b   = (const float*)d_in[3];
    const float* l0g   = (const float*)d_in[4];
    const float* l0be  = (const float*)d_in[5];
    const float* l0m   = (const float*)d_in[6];
    const float* l0v   = (const float*)d_in[7];
    const float* l1Wx  = (const float*)d_in[8];
    const float* l1Wh  = (const float*)d_in[9];
    const float* l1b   = (const float*)d_in[10];
    const float* l1g   = (const float*)d_in[11];
    const float* l1be  = (const float*)d_in[12];
    const float* l1m   = (const float*)d_in[13];
    const float* l1v   = (const float*)d_in[14];
    const float* dW    = (const float*)d_in[15];
    const float* dB    = (const float*)d_in[16];
    float* out = (float*)d_out;

    float* ws   = (float*)d_ws;
    float* zbuf = ws;                        // 2,097,152 f (8 MB)
    float* c0   = zbuf + 2097152;            // 524,288 f
    float* c1   = c0 + 524288;
    ushort* us  = (ushort*)(c1 + 524288);
    ushort* h0b = us;                        // 524,288 us
    ushort* h1b = h0b + 524288;
    ushort* xb  = h1b + 524288;              // 786,432 us
    ushort* x1  = xb + 786432;               // 16*524,288 us
    ushort* wf  = x1 + 8388608;              // 458,752 us

    prep_x<<<3072, 256, 0, stream>>>(in, xb);
    prep_w<<<1792, 256, 0, stream>>>(l0Wx, l0Wh, l1Wx, l1Wh, wf);
    init_zero<<<2048, 256, 0, stream>>>(c0, c1, h0b, h1b, out);

    // Layer 0
    for (int t = 0; t < Tn; ++t) {
        conv_mfma<<<512, 256, 0, stream>>>(xb + t * (PIX * CINc), CINc, 2, wf + FR_L0X,
                                           h0b, wf + FR_L0H, l0b, zbuf);
        gates_kernel<<<2048, 256, 0, stream>>>(zbuf, c0, h0b, x1 + t * (PIX * Fc),
                                               l0g, l0be, l0m, l0v);
    }
    // Layer 1
    for (int t = 0; t < Tn; ++t) {
        conv_mfma<<<512, 256, 0, stream>>>(x1 + t * (PIX * Fc), Fc, 18, wf + FR_L1X,
                                           h1b, wf + FR_L1H, l1b, zbuf);
        gates_kernel<<<2048, 256, 0, stream>>>(zbuf, c1, h1b, nullptr,
                                               nullptr, nullptr, nullptr, nullptr);
        pool_kernel<<<32, 256, 0, stream>>>(h1b, dW, dB, l1g, l1be, l1m, l1v, out);
    }
}

// Round 3
// 1032.502 us; speedup vs baseline: 4.2076x; 1.2221x over previous
//
#include <hip/hip_runtime.h>
#include <math.h>

typedef __attribute__((ext_vector_type(8))) short short8v;   // 8 bf16 = 4 VGPRs
typedef __attribute__((ext_vector_type(4))) float float4v;   // MFMA acc

constexpr int Bsz = 8, Tn = 16, CINc = 6, Fc = 64, NCc = 10;
constexpr int PIX = 8192;                 // 8*32*32 pixels per timestep
constexpr float BN_EPS = 1e-3f;

// weight-fragment region offsets (in ushort elements)
constexpr int FR_L0X = 0;                 // 2 chunks  (K=54 padded to 64)
constexpr int FR_L0H = 16384;             // 18 chunks (K=576)
constexpr int FR_L1X = 163840;            // 18 chunks
constexpr int FR_L1H = 311296;            // 18 chunks
constexpr int FR_TOTAL = 458752;

__device__ __forceinline__ ushort f2bf(float f) {
    union { float f; unsigned u; } v; v.f = f;
    unsigned r = v.u + 0x7FFFu + ((v.u >> 16) & 1u);   // RNE
    return (ushort)(r >> 16);
}
__device__ __forceinline__ float bf2f(ushort u) {
    union { unsigned u; float f; } v; v.u = ((unsigned)u) << 16; return v.f;
}
__device__ __forceinline__ float hsig(float x) {
    return fminf(fmaxf(0.2f * x + 0.5f, 0.0f), 1.0f);
}

#define GLDS(srcp, dstp) \
    __builtin_amdgcn_global_load_lds((const __attribute__((address_space(1))) void*)(srcp), \
                                     (__attribute__((address_space(3))) void*)(dstp), 16, 0, 0)

// ---------------- prep: x -> bf16 [t][pix][6] ----------------
__global__ __launch_bounds__(256) void prep_x(const float* __restrict__ in,
                                              ushort* __restrict__ xb) {
    int o = blockIdx.x * 256 + threadIdx.x;        // 16*8192*6 = 786432
    if (o >= Tn * PIX * CINc) return;
    int t = o / (PIX * CINc);
    int rem = o - t * (PIX * CINc);
    int pix = rem / CINc, c = rem - pix * CINc;
    int b = pix >> 10, p = pix & 1023;
    xb[o] = f2bf(in[((b * Tn + t) * 1024 + p) * CINc + c]);
}

// ---------------- prep: weights -> grouped B-fragment layout ----------------
// region layout: [kc][nh][j(0..7)][lane(0..63)][e(0..7)]; frag's nt = (j>>1)*4 + nh*2 + (j&1)
// element: k = kc*32 + (lane>>4)*4 + (e&3) + 16*(e>>2); n = nt*16 + (lane&15)
__global__ __launch_bounds__(256) void prep_w(const float* __restrict__ W0x,
                                              const float* __restrict__ W0h,
                                              const float* __restrict__ W1x,
                                              const float* __restrict__ W1h,
                                              ushort* __restrict__ F) {
    int o = blockIdx.x * 256 + threadIdx.x;
    if (o >= FR_TOTAL) return;
    const float* W; int K; int base;
    if (o < FR_L0H)      { W = W0x; K = 54;  base = FR_L0X; }
    else if (o < FR_L1X) { W = W0h; K = 576; base = FR_L0H; }
    else if (o < FR_L1H) { W = W1x; K = 576; base = FR_L1X; }
    else                 { W = W1h; K = 576; base = FR_L1H; }
    int r = o - base;
    int e = r & 7, lane = (r >> 3) & 63, j = (r >> 9) & 7, nh = (r >> 12) & 1, kc = r >> 13;
    int nt = ((j >> 1) << 2) + nh * 2 + (j & 1);
    int k = kc * 32 + ((lane >> 4) * 4) + (e & 3) + 16 * (e >> 2);
    int n = nt * 16 + (lane & 15);
    F[o] = (k < K) ? f2bf(W[k * 256 + n]) : (ushort)0;
}

// ---------------- init ----------------
__global__ __launch_bounds__(256) void init_zero(float* c0, float* c1,
                                                 ushort* h0, ushort* h1,
                                                 ushort* h0b, ushort* h1b, float* out) {
    int i = blockIdx.x * 256 + threadIdx.x;
    if (i < PIX * Fc) { c0[i] = 0.f; c1[i] = 0.f; h0[i] = 0; h1[i] = 0; h0b[i] = 0; h1b[i] = 0; }
    if (i < Bsz * NCc) out[i] = 0.f;
}

// ---------------- fused conv + gates ----------------
// block: 64 pixels x 128 gate-paired channels (nh half); 4 waves = 4 m-slices of 16 pix.
// Each wave holds 8 n-frags = {i,f,g,o} x 2 sub-frags -> gate math is register-local.
__global__ __launch_bounds__(256) void conv_fused(
    const ushort* __restrict__ Ax, int xCh, int xChunks, const ushort* __restrict__ BfX,
    const ushort* __restrict__ Ah, const ushort* __restrict__ BfH,
    const float* __restrict__ bias,
    float* __restrict__ C, ushort* __restrict__ Hout, ushort* __restrict__ X1out,
    const float* __restrict__ gamma, const float* __restrict__ beta,
    const float* __restrict__ mean, const float* __restrict__ var)
{
    __shared__ ushort As[64 * 40];        // 64 rows x 32k (+8 pad) = 80B rows
    __shared__ ushort Bs[2][4096];        // double-buffered 8KB B group

    const int tid = threadIdx.x;
    const int wid = tid >> 6, lane = tid & 63;
    const int bm = blockIdx.x >> 1, nh = blockIdx.x & 1;
    const int m0 = bm * 64;

    // A staging coords: thread stages pixel p_local, k-quarter kq (8 bf16 = 16B)
    const int p_local = tid >> 2, kq = tid & 3;
    const int p_global = m0 + p_local;
    const int img = p_global >> 10, pp = p_global & 1023;
    const int py = pp >> 5, px = pp & 31;

    const int arow_byte = (wid * 16 + (lane & 15)) * 80 + (lane >> 4) * 8;
    const int TOT = xChunks + 18;

    auto bgrp = [&](int q) -> const ushort* {
        return (q < xChunks) ? BfX + (((q * 2 + nh)) << 12)
                             : BfH + ((((q - xChunks) * 2 + nh)) << 12);
    };
    auto stageB = [&](int q, int buf) {
        const ushort* g = bgrp(q);
        GLDS(g + (tid << 3),         &Bs[buf][(wid) * 512]);
        GLDS(g + ((256 + tid) << 3), &Bs[buf][(4 + wid) * 512]);
    };
    auto gatherA = [&](int q) -> uint4 {
        uint4 av = make_uint4(0u, 0u, 0u, 0u);
        if (q >= xChunks) {                          // recurrent H path, Ch=64
            int kc = q - xChunks;
            int tap = kc >> 1;
            int c0h = ((kc & 1) << 5) + (kq << 3);
            int dy = tap / 3 - 1, dx = tap % 3 - 1;
            int gy = py + dy, gx = px + dx;
            if ((unsigned)gy < 32u && (unsigned)gx < 32u)
                av = *(const uint4*)(Ah + (((img << 10) + gy * 32 + gx) << 6) + c0h);
        } else if (xCh == 64) {                      // layer-1 X path
            int tap = q >> 1;
            int c0h = ((q & 1) << 5) + (kq << 3);
            int dy = tap / 3 - 1, dx = tap % 3 - 1;
            int gy = py + dy, gx = px + dx;
            if ((unsigned)gy < 32u && (unsigned)gx < 32u)
                av = *(const uint4*)(Ax + (((img << 10) + gy * 32 + gx) << 6) + c0h);
        } else {                                     // layer-0 X path, Ch=6, K=54 pad 64
            union { ushort s[8]; uint4 u; } pk;
#pragma unroll
            for (int j = 0; j < 8; ++j) {
                int kg = q * 32 + kq * 8 + j;
                ushort v = 0;
                if (kg < 54) {
                    int tap = kg / 6, c = kg - tap * 6;
                    int dy = tap / 3 - 1, dx = tap % 3 - 1;
                    int gy = py + dy, gx = px + dx;
                    if ((unsigned)gy < 32u && (unsigned)gx < 32u)
                        v = Ax[((img << 10) + gy * 32 + gx) * 6 + c];
                }
                pk.s[j] = v;
            }
            av = pk.u;
        }
        return av;
    };

    float4v acc[8];
#pragma unroll
    for (int j = 0; j < 8; ++j)
#pragma unroll
        for (int r = 0; r < 4; ++r) acc[j][r] = 0.f;

    // prologue
    uint4 av = gatherA(0);
    stageB(0, 0);

    for (int q = 0; q < TOT; ++q) {
        __syncthreads();    // drains glds of B(q); prior iter's LDS reads done
        *(uint4*)((char*)As + p_local * 80 + kq * 16) = av;
        __syncthreads();    // publish As (Bs[q&1] already visible)

        union { struct { uint2 lo, hi; } u; short8v s; } afr;
        afr.u.lo = *(const uint2*)((const char*)As + arow_byte);
        afr.u.hi = *(const uint2*)((const char*)As + arow_byte + 32);

        const ushort* bs = Bs[q & 1];
        union { uint4 u; short8v s; } bf[8];
#pragma unroll
        for (int j = 0; j < 8; ++j)
            bf[j].u = *(const uint4*)(bs + ((j * 64 + lane) << 3));

        // prefetch next chunk during MFMA region (drained at next top barrier)
        if (q + 1 < TOT) {
            stageB(q + 1, (q + 1) & 1);
            av = gatherA(q + 1);
        }

#pragma unroll
        for (int j = 0; j < 8; ++j)
            acc[j] = __builtin_amdgcn_mfma_f32_16x16x32_bf16(afr.s, bf[j].s, acc[j], 0, 0, 0);
    }

    // ---------------- fused gate epilogue ----------------
    // acc[j]: nt = (j>>1)*4 + nh*2 + (j&1): j=0,1 -> i; 2,3 -> f; 4,5 -> g; 6,7 -> o
#pragma unroll
    for (int jj = 0; jj < 2; ++jj) {
        const int ch = (nh * 2 + jj) * 16 + (lane & 15);   // h-channel 0..63
        const float bi = bias[ch], bfg = bias[64 + ch], bg = bias[128 + ch], bo = bias[192 + ch];
        float inv = 0.f, mu = 0.f, bet = 0.f;
        if (X1out) { inv = gamma[ch] * rsqrtf(var[ch] + BN_EPS); mu = mean[ch]; bet = beta[ch]; }
#pragma unroll
        for (int r = 0; r < 4; ++r) {
            const int p = m0 + wid * 16 + (lane >> 4) * 4 + r;
            const int o = p * 64 + ch;
            float zi = acc[0 + jj][r] + bi;
            float zf = acc[2 + jj][r] + bfg;
            float zg = acc[4 + jj][r] + bg;
            float zo = acc[6 + jj][r] + bo;
            float cv = hsig(zf) * C[o] + hsig(zi) * tanhf(zg);
            C[o] = cv;
            float h = hsig(zo) * tanhf(cv);
            Hout[o] = f2bf(h);
            if (X1out) X1out[o] = f2bf((h - mu) * inv + bet);
        }
    }
}

// ---------------- pool: BN1(h1) @ denseW -> softmax -> mean ----------------
__global__ __launch_bounds__(256) void pool_kernel(
    const ushort* __restrict__ H1, const float* __restrict__ dW,
    const float* __restrict__ dB,
    const float* __restrict__ gamma, const float* __restrict__ beta,
    const float* __restrict__ mean, const float* __restrict__ var,
    float* __restrict__ out)
{
    __shared__ float accs[NCc];
    int pix = blockIdx.x * 256 + threadIdx.x;   // 32 blocks x 256 = 8192
    int b = pix >> 10;
    if (threadIdx.x < NCc) accs[threadIdx.x] = 0.f;
    __syncthreads();

    float logit[NCc];
#pragma unroll
    for (int c = 0; c < NCc; ++c) logit[c] = dB[c];
    for (int f = 0; f < Fc; ++f) {
        float inv = gamma[f] * rsqrtf(var[f] + BN_EPS);
        float v = (bf2f(H1[pix * Fc + f]) - mean[f]) * inv + beta[f];
#pragma unroll
        for (int c = 0; c < NCc; ++c) logit[c] += v * dW[f * NCc + c];
    }
    float mx = logit[0];
#pragma unroll
    for (int c = 1; c < NCc; ++c) mx = fmaxf(mx, logit[c]);
    float p[NCc]; float s = 0.f;
#pragma unroll
    for (int c = 0; c < NCc; ++c) { p[c] = expf(logit[c] - mx); s += p[c]; }
    float invs = 1.f / s;
#pragma unroll
    for (int c = 0; c < NCc; ++c) atomicAdd(&accs[c], p[c] * invs);
    __syncthreads();
    if (threadIdx.x < NCc)
        atomicAdd(&out[b * NCc + threadIdx.x], accs[threadIdx.x] * (1.0f / 16384.0f));
}

extern "C" void kernel_launch(void* const* d_in, const int* in_sizes, int n_in,
                              void* d_out, int out_size, void* d_ws, size_t ws_size,
                              hipStream_t stream) {
    const float* in    = (const float*)d_in[0];
    const float* l0Wx  = (const float*)d_in[1];
    const float* l0Wh  = (const float*)d_in[2];
    const float* l0b   = (const float*)d_in[3];
    const float* l0g   = (const float*)d_in[4];
    const float* l0be  = (const float*)d_in[5];
    const float* l0m   = (const float*)d_in[6];
    const float* l0v   = (const float*)d_in[7];
    const float* l1Wx  = (const float*)d_in[8];
    const float* l1Wh  = (const float*)d_in[9];
    const float* l1b   = (const float*)d_in[10];
    const float* l1g   = (const float*)d_in[11];
    const float* l1be  = (const float*)d_in[12];
    const float* l1m   = (const float*)d_in[13];
    const float* l1v   = (const float*)d_in[14];
    const float* dW    = (const float*)d_in[15];
    const float* dB    = (const float*)d_in[16];
    float* out = (float*)d_out;

    float* ws   = (float*)d_ws;
    float* c0   = ws;                        // 524,288 f
    float* c1   = c0 + 524288;
    ushort* us  = (ushort*)(c1 + 524288);
    ushort* h0p0 = us;                       // h ping-pong buffers (bf16)
    ushort* h0p1 = h0p0 + 524288;
    ushort* h1p0 = h0p1 + 524288;
    ushort* h1p1 = h1p0 + 524288;
    ushort* xb  = h1p1 + 524288;             // 786,432 us
    ushort* x1  = xb + 786432;               // 16*524,288 us
    ushort* wf  = x1 + 8388608;              // 458,752 us

    ushort* h0p[2] = { h0p0, h0p1 };
    ushort* h1p[2] = { h1p0, h1p1 };

    prep_x<<<3072, 256, 0, stream>>>(in, xb);
    prep_w<<<1792, 256, 0, stream>>>(l0Wx, l0Wh, l1Wx, l1Wh, wf);
    init_zero<<<2048, 256, 0, stream>>>(c0, c1, h0p0, h1p0, h0p1, h1p1, out);

    // Layer 0 (reads h0p[t&1], writes h0p[(t+1)&1]; x1 gets BN'd output)
    for (int t = 0; t < Tn; ++t) {
        conv_fused<<<256, 256, 0, stream>>>(xb + t * (PIX * CINc), CINc, 2, wf + FR_L0X,
                                            h0p[t & 1], wf + FR_L0H, l0b,
                                            c0, h0p[(t + 1) & 1], x1 + t * (PIX * Fc),
                                            l0g, l0be, l0m, l0v);
    }
    // Layer 1
    for (int t = 0; t < Tn; ++t) {
        conv_fused<<<256, 256, 0, stream>>>(x1 + t * (PIX * Fc), Fc, 18, wf + FR_L1X,
                                            h1p[t & 1], wf + FR_L1H, l1b,
                                            c1, h1p[(t + 1) & 1], nullptr,
                                            nullptr, nullptr, nullptr, nullptr);
        pool_kernel<<<32, 256, 0, stream>>>(h1p[(t + 1) & 1], dW, dB, l1g, l1be, l1m, l1v, out);
    }
}

// Round 4
// 541.042 us; speedup vs baseline: 8.0296x; 1.9084x over previous
//
#include <hip/hip_runtime.h>
#include <math.h>

typedef __attribute__((ext_vector_type(8))) short short8v;   // 8 bf16 = 4 VGPRs
typedef __attribute__((ext_vector_type(4))) float float4v;   // MFMA acc

constexpr int Bsz = 8, Tn = 16, CINc = 6, Fc = 64, NCc = 10;
constexpr int PIX = 8192;                 // 8*32*32 pixels per timestep
constexpr float BN_EPS = 1e-3f;

// weight-fragment region offsets (in ushort elements)
constexpr int FR_L0X = 0;                 // 2 chunks  (K=54 padded to 64)
constexpr int FR_L0H = 16384;             // 18 chunks (K=576)
constexpr int FR_L1X = 163840;            // 18 chunks
constexpr int FR_L1H = 311296;            // 18 chunks
constexpr int FR_TOTAL = 458752;

__device__ __forceinline__ ushort f2bf(float f) {
    union { float f; unsigned u; } v; v.f = f;
    unsigned r = v.u + 0x7FFFu + ((v.u >> 16) & 1u);   // RNE
    return (ushort)(r >> 16);
}
__device__ __forceinline__ float bf2f(ushort u) {
    union { unsigned u; float f; } v; v.u = ((unsigned)u) << 16; return v.f;
}
__device__ __forceinline__ float hsig(float x) {
    return fminf(fmaxf(0.2f * x + 0.5f, 0.0f), 1.0f);
}

#define GLDS(srcp, dstp) \
    __builtin_amdgcn_global_load_lds((const __attribute__((address_space(1))) void*)(srcp), \
                                     (__attribute__((address_space(3))) void*)(dstp), 16, 0, 0)

// ---------------- prep: x -> bf16 [t][pix][6] ----------------
__global__ __launch_bounds__(256) void prep_x(const float* __restrict__ in,
                                              ushort* __restrict__ xb) {
    int o = blockIdx.x * 256 + threadIdx.x;        // 16*8192*6 = 786432
    if (o >= Tn * PIX * CINc) return;
    int t = o / (PIX * CINc);
    int rem = o - t * (PIX * CINc);
    int pix = rem / CINc, c = rem - pix * CINc;
    int b = pix >> 10, p = pix & 1023;
    xb[o] = f2bf(in[((b * Tn + t) * 1024 + p) * CINc + c]);
}

// ---------------- prep: weights -> grouped B-fragment layout ----------------
// region layout: [kc][nh][j(0..7)][lane(0..63)][e(0..7)]; frag's nt = (j>>1)*4 + nh*2 + (j&1)
// element: k = kc*32 + (lane>>4)*4 + (e&3) + 16*(e>>2); n = nt*16 + (lane&15)
__global__ __launch_bounds__(256) void prep_w(const float* __restrict__ W0x,
                                              const float* __restrict__ W0h,
                                              const float* __restrict__ W1x,
                                              const float* __restrict__ W1h,
                                              ushort* __restrict__ F) {
    int o = blockIdx.x * 256 + threadIdx.x;
    if (o >= FR_TOTAL) return;
    const float* W; int K; int base;
    if (o < FR_L0H)      { W = W0x; K = 54;  base = FR_L0X; }
    else if (o < FR_L1X) { W = W0h; K = 576; base = FR_L0H; }
    else if (o < FR_L1H) { W = W1x; K = 576; base = FR_L1X; }
    else                 { W = W1h; K = 576; base = FR_L1H; }
    int r = o - base;
    int e = r & 7, lane = (r >> 3) & 63, j = (r >> 9) & 7, nh = (r >> 12) & 1, kc = r >> 13;
    int nt = ((j >> 1) << 2) + nh * 2 + (j & 1);
    int k = kc * 32 + ((lane >> 4) * 4) + (e & 3) + 16 * (e >> 2);
    int n = nt * 16 + (lane & 15);
    F[o] = (k < K) ? f2bf(W[k * 256 + n]) : (ushort)0;
}

// ---------------- init ----------------
__global__ __launch_bounds__(256) void init_zero(float* c0, float* c1,
                                                 ushort* h0, ushort* h1,
                                                 ushort* h0b, ushort* h1b, float* out) {
    int i = blockIdx.x * 256 + threadIdx.x;
    if (i < PIX * Fc) { c0[i] = 0.f; c1[i] = 0.f; h0[i] = 0; h1[i] = 0; h0b[i] = 0; h1b[i] = 0; }
    if (i < Bsz * NCc) out[i] = 0.f;
}

// ---------------- batched input-conv GEMM: ZX[t] = conv(x_t, Wx) + bias ----------------
// grid: 16 t x 128 mtiles x 2 nh = 4096 blocks; block = 64 pix x 128 gate-ch (nh half)
__global__ __launch_bounds__(256) void zx_gemm(
    const ushort* __restrict__ X, int xCh, int xChunks,
    const ushort* __restrict__ Bf, const float* __restrict__ bias,
    float* __restrict__ ZX)
{
    __shared__ ushort As[64 * 40];        // 64 rows x 32k (+8 pad) = 80B rows
    __shared__ ushort Bs[2][4096];        // double-buffered 8KB B group

    const int tid = threadIdx.x;
    const int wid = tid >> 6, lane = tid & 63;
    const int bma = blockIdx.x >> 1, nh = blockIdx.x & 1;
    const int t = bma >> 7, bm = bma & 127;
    const int m0 = bm * 64;
    const ushort* __restrict__ Xt = X + t * PIX * xCh;
    float* __restrict__ ZXt = ZX + (size_t)t * PIX * 256;

    const int p_local = tid >> 2, kq = tid & 3;
    const int p_global = m0 + p_local;
    const int img = p_global >> 10, pp = p_global & 1023;
    const int py = pp >> 5, px = pp & 31;

    const int arow_byte = (wid * 16 + (lane & 15)) * 80 + (lane >> 4) * 8;

    auto stageB = [&](int q, int buf) {
        const ushort* g = Bf + ((q * 2 + nh) << 12);
        GLDS(g + (tid << 3),         &Bs[buf][(wid) * 512]);
        GLDS(g + ((256 + tid) << 3), &Bs[buf][(4 + wid) * 512]);
    };
    auto gatherA = [&](int q) -> uint4 {
        uint4 av = make_uint4(0u, 0u, 0u, 0u);
        if (xCh == 64) {
            int tap = q >> 1;
            int c0h = ((q & 1) << 5) + (kq << 3);
            int dy = tap / 3 - 1, dx = tap % 3 - 1;
            int gy = py + dy, gx = px + dx;
            if ((unsigned)gy < 32u && (unsigned)gx < 32u)
                av = *(const uint4*)(Xt + (((img << 10) + gy * 32 + gx) << 6) + c0h);
        } else {                                     // Ch=6, K=54 pad 64
            union { ushort s[8]; uint4 u; } pk;
#pragma unroll
            for (int j = 0; j < 8; ++j) {
                int kg = q * 32 + kq * 8 + j;
                ushort v = 0;
                if (kg < 54) {
                    int tap = kg / 6, c = kg - tap * 6;
                    int dy = tap / 3 - 1, dx = tap % 3 - 1;
                    int gy = py + dy, gx = px + dx;
                    if ((unsigned)gy < 32u && (unsigned)gx < 32u)
                        v = Xt[((img << 10) + gy * 32 + gx) * 6 + c];
                }
                pk.s[j] = v;
            }
            av = pk.u;
        }
        return av;
    };

    float4v acc[8];
#pragma unroll
    for (int j = 0; j < 8; ++j)
#pragma unroll
        for (int r = 0; r < 4; ++r) acc[j][r] = 0.f;

    uint4 av = gatherA(0);
    stageB(0, 0);

    for (int q = 0; q < xChunks; ++q) {
        __syncthreads();
        *(uint4*)((char*)As + p_local * 80 + kq * 16) = av;
        __syncthreads();

        union { struct { uint2 lo, hi; } u; short8v s; } afr;
        afr.u.lo = *(const uint2*)((const char*)As + arow_byte);
        afr.u.hi = *(const uint2*)((const char*)As + arow_byte + 32);

        const ushort* bs = Bs[q & 1];
        union { uint4 u; short8v s; } bf[8];
#pragma unroll
        for (int j = 0; j < 8; ++j)
            bf[j].u = *(const uint4*)(bs + ((j * 64 + lane) << 3));

        if (q + 1 < xChunks) {
            stageB(q + 1, (q + 1) & 1);
            av = gatherA(q + 1);
        }

#pragma unroll
        for (int j = 0; j < 8; ++j)
            acc[j] = __builtin_amdgcn_mfma_f32_16x16x32_bf16(afr.s, bf[j].s, acc[j], 0, 0, 0);
    }

    // store ZX (+bias)
#pragma unroll
    for (int j = 0; j < 8; ++j) {
        const int nt = ((j >> 1) << 2) + nh * 2 + (j & 1);
        const int n = nt * 16 + (lane & 15);
        const float bb = bias[n];
#pragma unroll
        for (int r = 0; r < 4; ++r) {
            const int p = m0 + wid * 16 + (lane >> 4) * 4 + r;
            ZXt[p * 256 + n] = acc[j][r] + bb;
        }
    }
}

// ---------------- sequential step: conv(h,Wh) + ZX -> gates -> h,c ----------------
// grid 256 = 128 mtiles x 2 nh
__global__ __launch_bounds__(256) void h_step(
    const ushort* __restrict__ Hprev, const ushort* __restrict__ BfH,
    const float* __restrict__ ZXt,
    float* __restrict__ C, ushort* __restrict__ Hout,
    ushort* __restrict__ Xtra, int doBN,
    const float* __restrict__ gamma, const float* __restrict__ beta,
    const float* __restrict__ mean, const float* __restrict__ var)
{
    __shared__ ushort As[64 * 40];
    __shared__ ushort Bs[2][4096];

    const int tid = threadIdx.x;
    const int wid = tid >> 6, lane = tid & 63;
    const int bm = blockIdx.x >> 1, nh = blockIdx.x & 1;
    const int m0 = bm * 64;

    const int p_local = tid >> 2, kq = tid & 3;
    const int p_global = m0 + p_local;
    const int img = p_global >> 10, pp = p_global & 1023;
    const int py = pp >> 5, px = pp & 31;

    const int arow_byte = (wid * 16 + (lane & 15)) * 80 + (lane >> 4) * 8;

    auto stageB = [&](int q, int buf) {
        const ushort* g = BfH + ((q * 2 + nh) << 12);
        GLDS(g + (tid << 3),         &Bs[buf][(wid) * 512]);
        GLDS(g + ((256 + tid) << 3), &Bs[buf][(4 + wid) * 512]);
    };
    auto gatherA = [&](int q) -> uint4 {
        uint4 av = make_uint4(0u, 0u, 0u, 0u);
        int tap = q >> 1;
        int c0h = ((q & 1) << 5) + (kq << 3);
        int dy = tap / 3 - 1, dx = tap % 3 - 1;
        int gy = py + dy, gx = px + dx;
        if ((unsigned)gy < 32u && (unsigned)gx < 32u)
            av = *(const uint4*)(Hprev + (((img << 10) + gy * 32 + gx) << 6) + c0h);
        return av;
    };

    // acc init from ZX (bias already folded in)
    float4v acc[8];
#pragma unroll
    for (int j = 0; j < 8; ++j) {
        const int nt = ((j >> 1) << 2) + nh * 2 + (j & 1);
        const int n = nt * 16 + (lane & 15);
#pragma unroll
        for (int r = 0; r < 4; ++r) {
            const int p = m0 + wid * 16 + (lane >> 4) * 4 + r;
            acc[j][r] = ZXt[p * 256 + n];
        }
    }

    uint4 av = gatherA(0);
    stageB(0, 0);

    for (int q = 0; q < 18; ++q) {
        __syncthreads();
        *(uint4*)((char*)As + p_local * 80 + kq * 16) = av;
        __syncthreads();

        union { struct { uint2 lo, hi; } u; short8v s; } afr;
        afr.u.lo = *(const uint2*)((const char*)As + arow_byte);
        afr.u.hi = *(const uint2*)((const char*)As + arow_byte + 32);

        const ushort* bs = Bs[q & 1];
        union { uint4 u; short8v s; } bf[8];
#pragma unroll
        for (int j = 0; j < 8; ++j)
            bf[j].u = *(const uint4*)(bs + ((j * 64 + lane) << 3));

        if (q + 1 < 18) {
            stageB(q + 1, (q + 1) & 1);
            av = gatherA(q + 1);
        }

#pragma unroll
        for (int j = 0; j < 8; ++j)
            acc[j] = __builtin_amdgcn_mfma_f32_16x16x32_bf16(afr.s, bf[j].s, acc[j], 0, 0, 0);
    }

    // fused gate epilogue: j=0,1 -> i; 2,3 -> f; 4,5 -> g; 6,7 -> o
#pragma unroll
    for (int jj = 0; jj < 2; ++jj) {
        const int ch = (nh * 2 + jj) * 16 + (lane & 15);   // h-channel 0..63
        float inv = 0.f, mu = 0.f, bet = 0.f;
        if (doBN) { inv = gamma[ch] * rsqrtf(var[ch] + BN_EPS); mu = mean[ch]; bet = beta[ch]; }
#pragma unroll
        for (int r = 0; r < 4; ++r) {
            const int p = m0 + wid * 16 + (lane >> 4) * 4 + r;
            const int o = p * 64 + ch;
            float zi = acc[0 + jj][r];
            float zf = acc[2 + jj][r];
            float zg = acc[4 + jj][r];
            float zo = acc[6 + jj][r];
            float cv = hsig(zf) * C[o] + hsig(zi) * tanhf(zg);
            C[o] = cv;
            float h = hsig(zo) * tanhf(cv);
            Hout[o] = f2bf(h);
            if (Xtra) Xtra[o] = doBN ? f2bf((h - mu) * inv + bet) : f2bf(h);
        }
    }
}

// ---------------- pool over all t: BN1(h1) @ denseW -> softmax -> mean ----------------
__global__ __launch_bounds__(256) void pool_all(
    const ushort* __restrict__ H1seq, const float* __restrict__ dW,
    const float* __restrict__ dB,
    const float* __restrict__ gamma, const float* __restrict__ beta,
    const float* __restrict__ mean, const float* __restrict__ var,
    float* __restrict__ out)
{
    __shared__ float accs[NCc];
    int gid = blockIdx.x * 256 + threadIdx.x;   // 512 blocks x 256 = 131072
    int pix = gid & 8191;
    int b = pix >> 10;
    if (threadIdx.x < NCc) accs[threadIdx.x] = 0.f;
    __syncthreads();

    float logit[NCc];
#pragma unroll
    for (int c = 0; c < NCc; ++c) logit[c] = dB[c];
    const ushort* hp = H1seq + (size_t)gid * Fc;
    for (int f0 = 0; f0 < Fc; f0 += 8) {
        uint4 hv = *(const uint4*)(hp + f0);
        union { uint4 u; ushort s[8]; } hu; hu.u = hv;
#pragma unroll
        for (int j = 0; j < 8; ++j) {
            int f = f0 + j;
            float inv = gamma[f] * rsqrtf(var[f] + BN_EPS);
            float v = (bf2f(hu.s[j]) - mean[f]) * inv + beta[f];
#pragma unroll
            for (int c = 0; c < NCc; ++c) logit[c] += v * dW[f * NCc + c];
        }
    }
    float mx = logit[0];
#pragma unroll
    for (int c = 1; c < NCc; ++c) mx = fmaxf(mx, logit[c]);
    float p[NCc]; float s = 0.f;
#pragma unroll
    for (int c = 0; c < NCc; ++c) { p[c] = expf(logit[c] - mx); s += p[c]; }
    float invs = 1.f / s;
#pragma unroll
    for (int c = 0; c < NCc; ++c) atomicAdd(&accs[c], p[c] * invs);
    __syncthreads();
    if (threadIdx.x < NCc)
        atomicAdd(&out[b * NCc + threadIdx.x], accs[threadIdx.x] * (1.0f / 16384.0f));
}

extern "C" void kernel_launch(void* const* d_in, const int* in_sizes, int n_in,
                              void* d_out, int out_size, void* d_ws, size_t ws_size,
                              hipStream_t stream) {
    const float* in    = (const float*)d_in[0];
    const float* l0Wx  = (const float*)d_in[1];
    const float* l0Wh  = (const float*)d_in[2];
    const float* l0b   = (const float*)d_in[3];
    const float* l0g   = (const float*)d_in[4];
    const float* l0be  = (const float*)d_in[5];
    const float* l0m   = (const float*)d_in[6];
    const float* l0v   = (const float*)d_in[7];
    const float* l1Wx  = (const float*)d_in[8];
    const float* l1Wh  = (const float*)d_in[9];
    const float* l1b   = (const float*)d_in[10];
    const float* l1g   = (const float*)d_in[11];
    const float* l1be  = (const float*)d_in[12];
    const float* l1m   = (const float*)d_in[13];
    const float* l1v   = (const float*)d_in[14];
    const float* dW    = (const float*)d_in[15];
    const float* dB    = (const float*)d_in[16];
    float* out = (float*)d_out;

    float* ws   = (float*)d_ws;
    float* c0   = ws;                        // 524,288 f
    float* c1   = c0 + 524288;
    float* zx   = c1 + 524288;               // 33,554,432 f (128 MB), reused per layer
    ushort* us  = (ushort*)(zx + 33554432);
    ushort* h0p0 = us;                       // h ping-pong buffers (bf16)
    ushort* h0p1 = h0p0 + 524288;
    ushort* h1p0 = h0p1 + 524288;
    ushort* h1p1 = h1p0 + 524288;
    ushort* xb  = h1p1 + 524288;             // 786,432 us
    ushort* x1  = xb + 786432;               // 16*524,288 us
    ushort* h1s = x1 + 8388608;              // 16*524,288 us
    ushort* wf  = h1s + 8388608;             // 458,752 us

    ushort* h0p[2] = { h0p0, h0p1 };
    ushort* h1p[2] = { h1p0, h1p1 };

    prep_x<<<3072, 256, 0, stream>>>(in, xb);
    prep_w<<<1792, 256, 0, stream>>>(l0Wx, l0Wh, l1Wx, l1Wh, wf);
    init_zero<<<2048, 256, 0, stream>>>(c0, c1, h0p0, h1p0, h0p1, h1p1, out);

    // Layer 0: batched input conv, then sequential h-steps
    zx_gemm<<<4096, 256, 0, stream>>>(xb, CINc, 2, wf + FR_L0X, l0b, zx);
    for (int t = 0; t < Tn; ++t) {
        h_step<<<256, 256, 0, stream>>>(h0p[t & 1], wf + FR_L0H, zx + (size_t)t * PIX * 256,
                                        c0, h0p[(t + 1) & 1], x1 + t * (PIX * Fc), 1,
                                        l0g, l0be, l0m, l0v);
    }
    // Layer 1
    zx_gemm<<<4096, 256, 0, stream>>>(x1, Fc, 18, wf + FR_L1X, l1b, zx);
    for (int t = 0; t < Tn; ++t) {
        h_step<<<256, 256, 0, stream>>>(h1p[t & 1], wf + FR_L1H, zx + (size_t)t * PIX * 256,
                                        c1, h1p[(t + 1) & 1], h1s + t * (PIX * Fc), 0,
                                        nullptr, nullptr, nullptr, nullptr);
    }
    pool_all<<<512, 256, 0, stream>>>(h1s, dW, dB, l1g, l1be, l1m, l1v, out);
}